// Round 9
// baseline (691.913 us; speedup 1.0000x reference)
//
#include <hip/hip_runtime.h>
#include <math.h>

static inline size_t align256(size_t x) { return (x + 255) & ~(size_t)255; }

#define NBLK 256    // edge partition chunks (and scan width)
#define NBUCK 256   // dst buckets: bucket = dst >> 9 (512 dsts/bucket, needs N <= 131072)

using short8 = __attribute__((ext_vector_type(8))) short;
using f32x4  = __attribute__((ext_vector_type(4))) float;

__device__ inline unsigned short f2bf(float f) {
  unsigned u = __float_as_uint(f);
  unsigned r = u + 0x7FFFu + ((u >> 16) & 1u);
  return (unsigned short)(r >> 16);
}
__device__ inline float bf2f(unsigned short h) {
  return __uint_as_float(((unsigned)h) << 16);
}

// ---------------- F1: per-chunk histogram over dst buckets ----------------
__global__ __launch_bounds__(512) void k_hist(const int* __restrict__ dst,
                                              int* __restrict__ H, int E) {
  __shared__ int h[NBUCK];
  for (int i = threadIdx.x; i < NBUCK; i += 512) h[i] = 0;
  __syncthreads();
  const int C = (E + NBLK - 1) / NBLK;
  const int lo = blockIdx.x * C, hi = min(E, lo + C);
  for (int e = lo + threadIdx.x; e < hi; e += 512)
    atomicAdd(&h[dst[e] >> 9], 1);
  __syncthreads();
  for (int i = threadIdx.x; i < NBUCK; i += 512)
    H[(size_t)blockIdx.x * NBUCK + i] = h[i];
}

// ---------------- F2a: per-bucket exclusive scan over chunks ----------------
__global__ __launch_bounds__(NBLK) void k_bscan(int* __restrict__ H,
                                                int* __restrict__ bsum) {
  __shared__ int sm[NBLK];
  const int b = blockIdx.x;
  int v = H[(size_t)threadIdx.x * NBUCK + b];
  sm[threadIdx.x] = v;
  __syncthreads();
  for (int off = 1; off < NBLK; off <<= 1) {
    int t = (threadIdx.x >= off) ? sm[threadIdx.x - off] : 0;
    __syncthreads();
    sm[threadIdx.x] += t;
    __syncthreads();
  }
  H[(size_t)threadIdx.x * NBUCK + b] = sm[threadIdx.x] - v;  // exclusive over chunks
  if (threadIdx.x == NBLK - 1) bsum[b] = sm[NBLK - 1];
}

// ---------------- F2b: exclusive scan of bucket totals (+ sentinel) ----------------
__global__ __launch_bounds__(NBUCK) void k_bstart(int* __restrict__ bsum, int E) {
  __shared__ int sm[NBUCK];
  int v = bsum[threadIdx.x];
  sm[threadIdx.x] = v;
  __syncthreads();
  for (int off = 1; off < NBUCK; off <<= 1) {
    int t = (threadIdx.x >= off) ? sm[threadIdx.x - off] : 0;
    __syncthreads();
    sm[threadIdx.x] += t;
    __syncthreads();
  }
  bsum[threadIdx.x] = sm[threadIdx.x] - v;
  if (threadIdx.x == NBUCK - 1) bsum[NBUCK] = E;  // sentinel
}

// ---------------- F3: partition edges into bucket regions (packed 4B) ----------------
__global__ __launch_bounds__(512) void k_part(const int* __restrict__ src,
                                              const int* __restrict__ dst,
                                              const int* __restrict__ H,
                                              const int* __restrict__ bstart,
                                              unsigned int* __restrict__ P, int E) {
  __shared__ int cur[NBUCK];
  for (int i = threadIdx.x; i < NBUCK; i += 512)
    cur[i] = bstart[i] + H[(size_t)blockIdx.x * NBUCK + i];
  __syncthreads();
  const int C = (E + NBLK - 1) / NBLK;
  const int lo = blockIdx.x * C, hi = min(E, lo + C);
  for (int e = lo + threadIdx.x; e < hi; e += 512) {
    int d = dst[e], s = src[e];
    int pos = atomicAdd(&cur[d >> 9], 1);
    P[pos] = ((unsigned)(d & 511) << 17) | (unsigned)s;  // needs src < 2^17
  }
}

// ---------------- F4: per-bucket local sort -> srcs + rowptr + deg + dinv ----------------
__global__ __launch_bounds__(512) void k_bucket(const unsigned int* __restrict__ P,
                                                const int* __restrict__ bstart,
                                                int* __restrict__ srcs,
                                                int* __restrict__ rowptr,
                                                int* __restrict__ deg,
                                                float* __restrict__ dinv,
                                                int n) {
  __shared__ int cnt[512], scn[512], cur[512];
  const int b = blockIdx.x;
  const int base = bstart[b], endp = bstart[b + 1];
  cnt[threadIdx.x] = 0;
  __syncthreads();
  for (int e = base + threadIdx.x; e < endp; e += 512)
    atomicAdd(&cnt[P[e] >> 17], 1);
  __syncthreads();
  int v = cnt[threadIdx.x];
  scn[threadIdx.x] = v;
  __syncthreads();
  for (int off = 1; off < 512; off <<= 1) {
    int t = (threadIdx.x >= off) ? scn[threadIdx.x - off] : 0;
    __syncthreads();
    scn[threadIdx.x] += t;
    __syncthreads();
  }
  const int ex = scn[threadIdx.x] - v;   // exclusive within bucket
  cur[threadIdx.x] = ex;
  const int d = (b << 9) + threadIdx.x;
  if (d < n) {
    rowptr[d] = base + ex;
    deg[d] = v;
    dinv[d] = rsqrtf((float)(v + 1));    // +1 self-loop
  }
  __syncthreads();
  for (int e = base + threadIdx.x; e < endp; e += 512) {
    unsigned p = P[e];
    int pos = base + atomicAdd(&cur[p >> 17], 1);
    srcs[pos] = (int)(p & 0x1FFFFu);
  }
}

// ---------------- gather-aggregate: wave per dst node ----------------
__global__ __launch_bounds__(256) void k_gather(const int* __restrict__ srcs,
                                                const int* __restrict__ rowptr,
                                                const int* __restrict__ deg,
                                                const float* __restrict__ dinv,
                                                const float* __restrict__ xw,
                                                const float* __restrict__ bias,
                                                float* __restrict__ out, int n) {
  int lane = threadIdx.x & 63;
  int i = (blockIdx.x * 256 + threadIdx.x) >> 6;
  if (i >= n) return;
  const int c = lane * 2;
  float di = dinv[i];
  const float2 self = *(const float2*)(xw + (size_t)i * 128 + c);
  const float2 bv = *(const float2*)(bias + c);
  float ax = fmaf(di * di, self.x, bv.x);
  float ay = fmaf(di * di, self.y, bv.y);

  int j = rowptr[i];
  int end = j + deg[i];
  for (; j + 4 <= end; j += 4) {
    int s0 = srcs[j], s1 = srcs[j + 1], s2i = srcs[j + 2], s3 = srcs[j + 3];
    float n0 = dinv[s0] * di, n1 = dinv[s1] * di;
    float n2 = dinv[s2i] * di, n3 = dinv[s3] * di;
    const float2 v0 = *(const float2*)(xw + (size_t)s0 * 128 + c);
    const float2 v1 = *(const float2*)(xw + (size_t)s1 * 128 + c);
    const float2 v2 = *(const float2*)(xw + (size_t)s2i * 128 + c);
    const float2 v3 = *(const float2*)(xw + (size_t)s3 * 128 + c);
    ax = fmaf(v0.x, n0, ax); ay = fmaf(v0.y, n0, ay);
    ax = fmaf(v1.x, n1, ax); ay = fmaf(v1.y, n1, ay);
    ax = fmaf(v2.x, n2, ax); ay = fmaf(v2.y, n2, ay);
    ax = fmaf(v3.x, n3, ax); ay = fmaf(v3.y, n3, ay);
  }
  for (; j < end; ++j) {
    int s = srcs[j];
    float nm = dinv[s] * di;
    const float2 v = *(const float2*)(xw + (size_t)s * 128 + c);
    ax = fmaf(v.x, nm, ax); ay = fmaf(v.y, nm, ay);
  }
  float2 o; o.x = ax; o.y = ay;
  *(float2*)(out + (size_t)i * 128 + c) = o;
}

// ---------------- W prep: split fp32 W[k][n] -> bf16 hi/lo transposed [n][k] ----------------
__global__ __launch_bounds__(256) void k_wprep(const float* __restrict__ W1,
                                               const float* __restrict__ W2,
                                               const float* __restrict__ W00,
                                               const float* __restrict__ W10,
                                               short* __restrict__ whiT,
                                               short* __restrict__ wloT) {
  const float* Wm = (blockIdx.y == 0) ? W1 : (blockIdx.y == 1) ? W2
                    : (blockIdx.y == 2) ? W00 : W10;
  short* ho = whiT + (size_t)blockIdx.y * 16384;
  short* lo = wloT + (size_t)blockIdx.y * 16384;
  for (int idx = threadIdx.x; idx < 16384; idx += 256) {
    int k = idx >> 7, nn = idx & 127;
    float v = Wm[idx];
    unsigned short h = f2bf(v);
    ho[nn * 128 + k] = (short)h;
    lo[nn * 128 + k] = (short)f2bf(v - bf2f(h));
  }
}

// ---------------- MFMA GEMM: C[n x 128] = (relu?) A @ W  (split-bf16, 3 products) ----------------
// Block: 256 thr = 4 waves; 64 rows/block; wave w owns rows w*16..w*16+15, all 128 cols.
template<bool RELU_A>
__global__ __launch_bounds__(256) void k_gemm_mfma(const float* __restrict__ A,
                                                   const short* __restrict__ whiT,
                                                   const short* __restrict__ wloT,
                                                   float* __restrict__ C, int n) {
  __shared__ short Ahi[64][136];   // stride 136 (272B): 2-way LDS conflicts only
  __shared__ short Alo[64][136];
  const int tid = threadIdx.x;
  const size_t row0 = (size_t)blockIdx.x * 64;

  // stage A -> bf16 hi/lo
  {
    const int c4 = (tid & 31) << 2;
    const int rb = tid >> 5;
#pragma unroll
    for (int p = 0; p < 8; ++p) {
      const int r = rb + p * 8;
      const size_t gr = row0 + r;
      float4 av = make_float4(0.f, 0.f, 0.f, 0.f);
      if (gr < (size_t)n) {
        av = *(const float4*)(A + gr * 128 + c4);
        if (RELU_A) {
          av.x = fmaxf(av.x, 0.f); av.y = fmaxf(av.y, 0.f);
          av.z = fmaxf(av.z, 0.f); av.w = fmaxf(av.w, 0.f);
        }
      }
      short4 h, l;
      h.x = (short)f2bf(av.x); l.x = (short)f2bf(av.x - bf2f((unsigned short)h.x));
      h.y = (short)f2bf(av.y); l.y = (short)f2bf(av.y - bf2f((unsigned short)h.y));
      h.z = (short)f2bf(av.z); l.z = (short)f2bf(av.z - bf2f((unsigned short)h.z));
      h.w = (short)f2bf(av.w); l.w = (short)f2bf(av.w - bf2f((unsigned short)h.w));
      *(short4*)&Ahi[r][c4] = h;
      *(short4*)&Alo[r][c4] = l;
    }
  }
  __syncthreads();

  const int wid = tid >> 6, l = tid & 63;
  const int lo16 = l & 15, kg = l >> 4;
  const int arow = wid * 16 + lo16;

  f32x4 acc[8];
#pragma unroll
  for (int i = 0; i < 8; ++i) acc[i] = (f32x4){0.f, 0.f, 0.f, 0.f};

#pragma unroll
  for (int kb = 0; kb < 4; ++kb) {
    const int koff = kb * 32 + kg * 8;
    const short8 ah = *(const short8*)&Ahi[arow][koff];
    const short8 al = *(const short8*)&Alo[arow][koff];
#pragma unroll
    for (int nt = 0; nt < 8; ++nt) {
      const int wrow = (nt * 16 + lo16) * 128 + koff;
      const short8 bh = *(const short8*)(whiT + wrow);
      const short8 bl = *(const short8*)(wloT + wrow);
      acc[nt] = __builtin_amdgcn_mfma_f32_16x16x32_bf16(ah, bh, acc[nt], 0, 0, 0);
      acc[nt] = __builtin_amdgcn_mfma_f32_16x16x32_bf16(ah, bl, acc[nt], 0, 0, 0);
      acc[nt] = __builtin_amdgcn_mfma_f32_16x16x32_bf16(al, bh, acc[nt], 0, 0, 0);
    }
  }

  // C/D: row=(l>>4)*4+reg, col=l&15 (m89-verified)
  const size_t rbase = row0 + wid * 16 + kg * 4;
#pragma unroll
  for (int nt = 0; nt < 8; ++nt) {
    const int col = nt * 16 + lo16;
#pragma unroll
    for (int r = 0; r < 4; ++r) {
      const size_t gr = rbase + r;
      if (gr < (size_t)n) C[gr * 128 + col] = acc[nt][r];
    }
  }
}

// ---------------- MFMA fused heads ----------------
// rep = relu(rep_pre). p1 = sigmoid(rep.Wpp+bpp);
// yh = relu(rep@W h + b h) . w2 h ; y = t ? y1+b11 : y0+b01.
__global__ __launch_bounds__(256) void k_heads_mfma(const float* __restrict__ rep_pre,
                                                    const short* __restrict__ whiT0,
                                                    const short* __restrict__ wloT0,
                                                    const short* __restrict__ whiT1,
                                                    const short* __restrict__ wloT1,
                                                    const float* __restrict__ b00,
                                                    const float* __restrict__ b10,
                                                    const float* __restrict__ W01,
                                                    const float* __restrict__ b01,
                                                    const float* __restrict__ W11,
                                                    const float* __restrict__ b11,
                                                    const float* __restrict__ Wpp,
                                                    const float* __restrict__ bpp,
                                                    const int* __restrict__ t,
                                                    float* __restrict__ out, int n) {
  __shared__ short Ahi[64][136];
  __shared__ short Alo[64][136];
  const int tid = threadIdx.x;
  const size_t row0 = (size_t)blockIdx.x * 64;

  // stage relu(rep) -> bf16 hi/lo
  {
    const int c4 = (tid & 31) << 2;
    const int rb = tid >> 5;
#pragma unroll
    for (int p = 0; p < 8; ++p) {
      const int r = rb + p * 8;
      const size_t gr = row0 + r;
      float4 av = make_float4(0.f, 0.f, 0.f, 0.f);
      if (gr < (size_t)n) {
        av = *(const float4*)(rep_pre + gr * 128 + c4);
        av.x = fmaxf(av.x, 0.f); av.y = fmaxf(av.y, 0.f);
        av.z = fmaxf(av.z, 0.f); av.w = fmaxf(av.w, 0.f);
      }
      short4 h, l;
      h.x = (short)f2bf(av.x); l.x = (short)f2bf(av.x - bf2f((unsigned short)h.x));
      h.y = (short)f2bf(av.y); l.y = (short)f2bf(av.y - bf2f((unsigned short)h.y));
      h.z = (short)f2bf(av.z); l.z = (short)f2bf(av.z - bf2f((unsigned short)h.z));
      h.w = (short)f2bf(av.w); l.w = (short)f2bf(av.w - bf2f((unsigned short)h.w));
      *(short4*)&Ahi[r][c4] = h;
      *(short4*)&Alo[r][c4] = l;
    }
  }
  __syncthreads();

  const int wid = tid >> 6, l = tid & 63;
  const int lo16 = l & 15, kg = l >> 4;
  const int arow = wid * 16 + lo16;

  // ---- p1: rep . Wpp from A fragments (row = arow) ----
  {
    float pp = 0.f;
#pragma unroll
    for (int kb = 0; kb < 4; ++kb) {
      const int koff = kb * 32 + kg * 8;
      const short8 ah = *(const short8*)&Ahi[arow][koff];
      const short8 al = *(const short8*)&Alo[arow][koff];
      const float* wp = Wpp + koff;
#pragma unroll
      for (int j = 0; j < 8; ++j) {
        float av = bf2f((unsigned short)ah[j]) + bf2f((unsigned short)al[j]);
        pp = fmaf(av, wp[j], pp);
      }
    }
    pp += __shfl_xor(pp, 16, 64);
    pp += __shfl_xor(pp, 32, 64);
    if (kg == 0) {
      const size_t gr = row0 + arow;
      if (gr < (size_t)n) out[gr] = 1.f / (1.f + expf(-(pp + bpp[0])));
    }
  }

  float yv[2][4];
#pragma unroll
  for (int h = 0; h < 2; ++h) {
    const short* wh = h ? whiT1 : whiT0;
    const short* wl = h ? wloT1 : wloT0;
    const float* bb = h ? b10 : b00;
    const float* w2 = h ? W11 : W01;

    f32x4 acc[8];
#pragma unroll
    for (int i = 0; i < 8; ++i) acc[i] = (f32x4){0.f, 0.f, 0.f, 0.f};

#pragma unroll
    for (int kb = 0; kb < 4; ++kb) {
      const int koff = kb * 32 + kg * 8;
      const short8 ah = *(const short8*)&Ahi[arow][koff];
      const short8 al = *(const short8*)&Alo[arow][koff];
#pragma unroll
      for (int nt = 0; nt < 8; ++nt) {
        const int wrow = (nt * 16 + lo16) * 128 + koff;
        const short8 bh = *(const short8*)(wh + wrow);
        const short8 bl = *(const short8*)(wl + wrow);
        acc[nt] = __builtin_amdgcn_mfma_f32_16x16x32_bf16(ah, bh, acc[nt], 0, 0, 0);
        acc[nt] = __builtin_amdgcn_mfma_f32_16x16x32_bf16(ah, bl, acc[nt], 0, 0, 0);
        acc[nt] = __builtin_amdgcn_mfma_f32_16x16x32_bf16(al, bh, acc[nt], 0, 0, 0);
      }
    }

    float part[4] = {0.f, 0.f, 0.f, 0.f};
#pragma unroll
    for (int nt = 0; nt < 8; ++nt) {
      const int col = nt * 16 + lo16;
      const float bc = bb[col], wc = w2[col];
#pragma unroll
      for (int r = 0; r < 4; ++r)
        part[r] = fmaf(fmaxf(acc[nt][r] + bc, 0.f), wc, part[r]);
    }
#pragma unroll
    for (int r = 0; r < 4; ++r) {
      float v = part[r];
      v += __shfl_xor(v, 1, 64);
      v += __shfl_xor(v, 2, 64);
      v += __shfl_xor(v, 4, 64);
      v += __shfl_xor(v, 8, 64);
      yv[h][r] = v;
    }
  }

  if (lo16 == 0) {
#pragma unroll
    for (int r = 0; r < 4; ++r) {
      const size_t gr = row0 + wid * 16 + kg * 4 + r;
      if (gr < (size_t)n)
        out[n + gr] = (t[gr] > 0) ? (yv[1][r] + b11[0]) : (yv[0][r] + b01[0]);
    }
  }
}

// ---------------- legacy fp32 path (fallback only) ----------------
__global__ __launch_bounds__(256) void k_deg_init1(int* __restrict__ deg, int n) {
  int i = blockIdx.x * 256 + threadIdx.x;
  if (i < n) deg[i] = 1;
}
__global__ __launch_bounds__(256) void k_deg_count(const int* __restrict__ dst,
                                                   int* __restrict__ deg, int E) {
  int e = blockIdx.x * 256 + threadIdx.x;
  if (e < E) atomicAdd(&deg[dst[e]], 1);
}
__global__ __launch_bounds__(256) void k_dinv0(const int* __restrict__ deg,
                                               float* __restrict__ dinv, int n) {
  int i = blockIdx.x * 256 + threadIdx.x;
  if (i < n) dinv[i] = rsqrtf((float)deg[i]);
}
__global__ __launch_bounds__(256) void k_selfinit(const float* __restrict__ xw,
                                                  const float* __restrict__ dinv,
                                                  const float* __restrict__ bias,
                                                  float* __restrict__ agg, int n) {
  int idx = blockIdx.x * 256 + threadIdx.x;
  if (idx >= n * 32) return;
  int i = idx >> 5;
  int c = (idx & 31) << 2;
  float di = dinv[i];
  float s = di * di;
  const float4 v = *(const float4*)(xw + (size_t)i * 128 + c);
  const float4 b = *(const float4*)(bias + c);
  float4 o;
  o.x = fmaf(s, v.x, b.x);
  o.y = fmaf(s, v.y, b.y);
  o.z = fmaf(s, v.z, b.z);
  o.w = fmaf(s, v.w, b.w);
  *(float4*)(agg + (size_t)i * 128 + c) = o;
}
__global__ __launch_bounds__(256) void k_scatter(const int* __restrict__ src,
                                                 const int* __restrict__ dst,
                                                 const float* __restrict__ dinv,
                                                 const float* __restrict__ xw,
                                                 float* __restrict__ agg, int E) {
  int lane = threadIdx.x & 63;
  int e = (blockIdx.x * 256 + threadIdx.x) >> 6;
  if (e >= E) return;
  int s = src[e], d = dst[e];
  float nrm = dinv[s] * dinv[d];
  const float2 v = *(const float2*)(xw + (size_t)s * 128 + lane * 2);
  float* base = agg + (size_t)d * 128 + lane * 2;
  atomicAdd(base, v.x * nrm);
  atomicAdd(base + 1, v.y * nrm);
}

template<bool RELU_A>
__global__ __launch_bounds__(256) void k_gemm(const float* __restrict__ A,
                                              const float* __restrict__ W,
                                              float* __restrict__ C, int n) {
  __shared__ float As[64][132];
  __shared__ float Ws[128][68];
  const int tid = threadIdx.x;
  const int ct = blockIdx.x;
  const size_t row0 = (size_t)blockIdx.y * 64;
  {
    int c = (tid & 15) << 2;
    int kb = tid >> 4;
#pragma unroll
    for (int p = 0; p < 8; ++p) {
      int k = kb + p * 16;
      const float4 wv = *(const float4*)(W + (size_t)k * 128 + ct * 64 + c);
      *(float4*)&Ws[k][c] = wv;
    }
  }
  {
    int c = (tid & 31) << 2;
    int rb = tid >> 5;
#pragma unroll
    for (int p = 0; p < 8; ++p) {
      int r = rb + p * 8;
      size_t gr = row0 + r;
      float4 av = make_float4(0.f, 0.f, 0.f, 0.f);
      if (gr < (size_t)n) {
        av = *(const float4*)(A + gr * 128 + c);
        if (RELU_A) {
          av.x = fmaxf(av.x, 0.f); av.y = fmaxf(av.y, 0.f);
          av.z = fmaxf(av.z, 0.f); av.w = fmaxf(av.w, 0.f);
        }
      }
      *(float4*)&As[r][c] = av;
    }
  }
  __syncthreads();
  const int tx = tid & 15, ty = tid >> 4;
  const int r0 = ty << 2, c0 = tx << 2;
  float acc[4][4] = {{0.f}};
#pragma unroll 4
  for (int k = 0; k < 128; ++k) {
    const float4 wv = *(const float4*)&Ws[k][c0];
    float a[4];
#pragma unroll
    for (int i = 0; i < 4; ++i) a[i] = As[r0 + i][k];
#pragma unroll
    for (int i = 0; i < 4; ++i) {
      acc[i][0] = fmaf(a[i], wv.x, acc[i][0]);
      acc[i][1] = fmaf(a[i], wv.y, acc[i][1]);
      acc[i][2] = fmaf(a[i], wv.z, acc[i][2]);
      acc[i][3] = fmaf(a[i], wv.w, acc[i][3]);
    }
  }
#pragma unroll
  for (int i = 0; i < 4; ++i) {
    size_t gr = row0 + r0 + i;
    if (gr < (size_t)n) {
      float4 o;
      o.x = acc[i][0]; o.y = acc[i][1]; o.z = acc[i][2]; o.w = acc[i][3];
      *(float4*)(C + gr * 128 + ct * 64 + c0) = o;
    }
  }
}

__global__ __launch_bounds__(256) void k_heads(const float* __restrict__ rep_pre,
                                               const float* __restrict__ W00,
                                               const float* __restrict__ b00,
                                               const float* __restrict__ W10,
                                               const float* __restrict__ b10,
                                               const float* __restrict__ W01,
                                               const float* __restrict__ b01,
                                               const float* __restrict__ W11,
                                               const float* __restrict__ b11,
                                               const float* __restrict__ Wpp,
                                               const float* __restrict__ bpp,
                                               const int* __restrict__ t,
                                               float* __restrict__ out, int n) {
  __shared__ float As[64][132];
  __shared__ float Ws[128][68];
  const int tid = threadIdx.x;
  const size_t row0 = (size_t)blockIdx.x * 64;
  {
    int c = (tid & 31) << 2;
    int rb = tid >> 5;
#pragma unroll
    for (int p = 0; p < 8; ++p) {
      int r = rb + p * 8;
      size_t gr = row0 + r;
      float4 av = make_float4(0.f, 0.f, 0.f, 0.f);
      if (gr < (size_t)n) {
        av = *(const float4*)(rep_pre + gr * 128 + c);
        av.x = fmaxf(av.x, 0.f); av.y = fmaxf(av.y, 0.f);
        av.z = fmaxf(av.z, 0.f); av.w = fmaxf(av.w, 0.f);
      }
      *(float4*)&As[r][c] = av;
    }
  }
  __syncthreads();
  {
    int r = tid >> 2;
    int ko = (tid & 3) * 32;
    float v = 0.f;
#pragma unroll 8
    for (int kk = 0; kk < 32; ++kk) v = fmaf(As[r][ko + kk], Wpp[ko + kk], v);
    v += __shfl_xor(v, 1, 64);
    v += __shfl_xor(v, 2, 64);
    if ((tid & 3) == 0) {
      size_t gr = row0 + r;
      if (gr < (size_t)n) out[gr] = 1.f / (1.f + expf(-(v + bpp[0])));
    }
  }
  const int tx = tid & 15, ty = tid >> 4;
  const int r0 = ty << 2, c0 = tx << 2;
  float yv[2][4];
#pragma unroll
  for (int h = 0; h < 2; ++h) {
    const float* W  = h ? W10 : W00;
    const float* bb = h ? b10 : b00;
    const float* w2 = h ? W11 : W01;
    float part[4] = {0.f, 0.f, 0.f, 0.f};
    for (int half = 0; half < 2; ++half) {
      __syncthreads();
      {
        int c = (tid & 15) << 2;
        int kb = tid >> 4;
#pragma unroll
        for (int p = 0; p < 8; ++p) {
          int k = kb + p * 16;
          const float4 wv = *(const float4*)(W + (size_t)k * 128 + half * 64 + c);
          *(float4*)&Ws[k][c] = wv;
        }
      }
      __syncthreads();
      float acc[4][4] = {{0.f}};
#pragma unroll 4
      for (int k = 0; k < 128; ++k) {
        const float4 wv = *(const float4*)&Ws[k][c0];
        float a[4];
#pragma unroll
        for (int i = 0; i < 4; ++i) a[i] = As[r0 + i][k];
#pragma unroll
        for (int i = 0; i < 4; ++i) {
          acc[i][0] = fmaf(a[i], wv.x, acc[i][0]);
          acc[i][1] = fmaf(a[i], wv.y, acc[i][1]);
          acc[i][2] = fmaf(a[i], wv.z, acc[i][2]);
          acc[i][3] = fmaf(a[i], wv.w, acc[i][3]);
        }
      }
      const float4 bv = *(const float4*)(bb + half * 64 + c0);
      const float4 w2v = *(const float4*)(w2 + half * 64 + c0);
#pragma unroll
      for (int i = 0; i < 4; ++i) {
        part[i] = fmaf(fmaxf(acc[i][0] + bv.x, 0.f), w2v.x, part[i]);
        part[i] = fmaf(fmaxf(acc[i][1] + bv.y, 0.f), w2v.y, part[i]);
        part[i] = fmaf(fmaxf(acc[i][2] + bv.z, 0.f), w2v.z, part[i]);
        part[i] = fmaf(fmaxf(acc[i][3] + bv.w, 0.f), w2v.w, part[i]);
      }
    }
#pragma unroll
    for (int i = 0; i < 4; ++i) {
      float v = part[i];
      v += __shfl_xor(v, 1, 64);
      v += __shfl_xor(v, 2, 64);
      v += __shfl_xor(v, 4, 64);
      v += __shfl_xor(v, 8, 64);
      yv[h][i] = v;
    }
  }
  if (tx == 0) {
#pragma unroll
    for (int i = 0; i < 4; ++i) {
      size_t gr = row0 + r0 + i;
      if (gr < (size_t)n) {
        float v = (t[gr] > 0) ? (yv[1][i] + b11[0]) : (yv[0][i] + b01[0]);
        out[n + gr] = v;
      }
    }
  }
}

extern "C" void kernel_launch(void* const* d_in, const int* in_sizes, int n_in,
                              void* d_out, int out_size, void* d_ws, size_t ws_size,
                              hipStream_t stream) {
  const float* x   = (const float*)d_in[0];
  const int*   t   = (const int*)d_in[1];
  const int*   ei  = (const int*)d_in[3];
  const float* W1  = (const float*)d_in[4];
  const float* b1  = (const float*)d_in[5];
  const float* W2  = (const float*)d_in[6];
  const float* b2  = (const float*)d_in[7];
  const float* W00 = (const float*)d_in[8];
  const float* b00 = (const float*)d_in[9];
  const float* W10 = (const float*)d_in[10];
  const float* b10 = (const float*)d_in[11];
  const float* W01 = (const float*)d_in[12];
  const float* b01 = (const float*)d_in[13];
  const float* W11 = (const float*)d_in[14];
  const float* b11 = (const float*)d_in[15];
  const float* Wpp = (const float*)d_in[16];
  const float* bpp = (const float*)d_in[17];

  const int N = in_sizes[0] / 128;
  const int E = in_sizes[3] / 2;
  const int* srcp = ei;
  const int* dstp = ei + E;

  const size_t S = (size_t)N * 128 * sizeof(float);
  const int nbN = (N + 255) / 256;
  const int nbE = (E + 255) / 256;
  const int nbWaveN = (N + 3) / 4;
  const int nbRow64 = (N + 63) / 64;
  float* out = (float*)d_out;

  // workspace layout
  char* ws = (char*)d_ws;
  float* B1  = (float*)ws; ws += align256(S);
  float* B2  = (float*)ws; ws += align256(S);
  int*   deg = (int*)ws;   ws += align256((size_t)N * 4);
  float* dnv = (float*)ws; ws += align256((size_t)N * 4);
  int*   rowptr = (int*)ws; ws += align256((size_t)N * 4);
  int*   H      = (int*)ws; ws += align256((size_t)NBLK * NBUCK * 4);
  int*   bstart = (int*)ws; ws += align256((size_t)(NBUCK + 1) * 4);
  unsigned int* P = (unsigned int*)ws; ws += align256((size_t)E * 4);
  int*   srcs   = (int*)ws; ws += align256((size_t)E * 4);
  short* whiT   = (short*)ws; ws += align256((size_t)4 * 16384 * 2);
  short* wloT   = (short*)ws; ws += align256((size_t)4 * 16384 * 2);
  size_t need = (size_t)(ws - (char*)d_ws);

  // fast path requires: ws fits, dst < NBUCK*512, src < 2^17
  const bool csr_ok = (need <= ws_size) && (N <= NBUCK * 512) && (N <= (1 << 17));

  if (csr_ok) {
    // ---- W split prep (bf16 hi/lo, transposed) ----
    k_wprep<<<dim3(1, 4), 256, 0, stream>>>(W1, W2, W00, W10, whiT, wloT);

    // ---- CSR build via two-level bucket sort (no global atomics) ----
    k_hist  <<<NBLK, 512, 0, stream>>>(dstp, H, E);
    k_bscan <<<NBUCK, NBLK, 0, stream>>>(H, bstart);
    k_bstart<<<1, NBUCK, 0, stream>>>(bstart, E);
    k_part  <<<NBLK, 512, 0, stream>>>(srcp, dstp, H, bstart, P, E);
    k_bucket<<<NBUCK, 512, 0, stream>>>(P, bstart, srcs, rowptr, deg, dnv, N);

    // ---- layer 1 ----
    k_gemm_mfma<false><<<nbRow64, 256, 0, stream>>>(x, whiT, wloT, B1, N);
    k_gather<<<nbWaveN, 256, 0, stream>>>(srcs, rowptr, deg, dnv, B1, b1, B2, N);
    // ---- layer 2 ----
    k_gemm_mfma<true><<<nbRow64, 256, 0, stream>>>(B2, whiT + 16384, wloT + 16384, B1, N);
    k_gather<<<nbWaveN, 256, 0, stream>>>(srcs, rowptr, deg, dnv, B1, b2, B2, N);

    // ---- fused heads ----
    k_heads_mfma<<<nbRow64, 256, 0, stream>>>(B2,
        whiT + 2 * 16384, wloT + 2 * 16384, whiT + 3 * 16384, wloT + 3 * 16384,
        b00, b10, W01, b01, W11, b11, Wpp, bpp, t, out, N);
  } else {
    // ---- fallback: atomic scatter + fp32 VALU path ----
    const int nbNode32 = (N * 32 + 255) / 256;
    const int nbWaveE = (int)(((size_t)E * 64 + 255) / 256);
    dim3 gemmGrid(2, nbRow64);
    k_deg_init1<<<nbN, 256, 0, stream>>>(deg, N);
    k_deg_count<<<nbE, 256, 0, stream>>>(dstp, deg, E);
    k_dinv0<<<nbN, 256, 0, stream>>>(deg, dnv, N);
    k_gemm<false><<<gemmGrid, 256, 0, stream>>>(x, W1, B1, N);
    k_selfinit<<<nbNode32, 256, 0, stream>>>(B1, dnv, b1, B2, N);
    k_scatter<<<nbWaveE, 256, 0, stream>>>(srcp, dstp, dnv, B1, B2, E);
    k_gemm<true><<<gemmGrid, 256, 0, stream>>>(B2, W2, B1, N);
    k_selfinit<<<nbNode32, 256, 0, stream>>>(B1, dnv, b2, B2, N);
    k_scatter<<<nbWaveE, 256, 0, stream>>>(srcp, dstp, dnv, B1, B2, E);
    k_heads<<<nbRow64, 256, 0, stream>>>(B2, W00, b00, W10, b10, W01, b01,
                                         W11, b11, Wpp, bpp, t, out, N);
  }
}

// Round 13
// 498.329 us; speedup vs baseline: 1.3885x; 1.3885x over previous
//
#include <hip/hip_runtime.h>
#include <math.h>

static inline size_t align256(size_t x) { return (x + 255) & ~(size_t)255; }

#define NBLK 256    // edge partition chunks (and scan width)
#define NBUCK 256   // dst buckets: bucket = dst >> 9 (512 dsts/bucket, needs N <= 131072)

using short8 = __attribute__((ext_vector_type(8))) short;
using f32x4  = __attribute__((ext_vector_type(4))) float;

__device__ inline unsigned short f2bf(float f) {
  unsigned u = __float_as_uint(f);
  unsigned r = u + 0x7FFFu + ((u >> 16) & 1u);
  return (unsigned short)(r >> 16);
}
__device__ inline float bf2f(unsigned short h) {
  return __uint_as_float(((unsigned)h) << 16);
}

// ---------------- F1: per-chunk histogram over dst buckets ----------------
__global__ __launch_bounds__(512) void k_hist(const int* __restrict__ dst,
                                              int* __restrict__ H, int E) {
  __shared__ int h[NBUCK];
  for (int i = threadIdx.x; i < NBUCK; i += 512) h[i] = 0;
  __syncthreads();
  const int C = (E + NBLK - 1) / NBLK;
  const int lo = blockIdx.x * C, hi = min(E, lo + C);
  for (int e = lo + threadIdx.x; e < hi; e += 512)
    atomicAdd(&h[dst[e] >> 9], 1);
  __syncthreads();
  for (int i = threadIdx.x; i < NBUCK; i += 512)
    H[(size_t)blockIdx.x * NBUCK + i] = h[i];
}

// ---------------- F2a: per-bucket exclusive scan over chunks ----------------
__global__ __launch_bounds__(NBLK) void k_bscan(int* __restrict__ H,
                                                int* __restrict__ bsum) {
  __shared__ int sm[NBLK];
  const int b = blockIdx.x;
  int v = H[(size_t)threadIdx.x * NBUCK + b];
  sm[threadIdx.x] = v;
  __syncthreads();
  for (int off = 1; off < NBLK; off <<= 1) {
    int t = (threadIdx.x >= off) ? sm[threadIdx.x - off] : 0;
    __syncthreads();
    sm[threadIdx.x] += t;
    __syncthreads();
  }
  H[(size_t)threadIdx.x * NBUCK + b] = sm[threadIdx.x] - v;  // exclusive over chunks
  if (threadIdx.x == NBLK - 1) bsum[b] = sm[NBLK - 1];
}

// ---------------- F2b: exclusive scan of bucket totals (+ sentinel) ----------------
__global__ __launch_bounds__(NBUCK) void k_bstart(int* __restrict__ bsum, int E) {
  __shared__ int sm[NBUCK];
  int v = bsum[threadIdx.x];
  sm[threadIdx.x] = v;
  __syncthreads();
  for (int off = 1; off < NBUCK; off <<= 1) {
    int t = (threadIdx.x >= off) ? sm[threadIdx.x - off] : 0;
    __syncthreads();
    sm[threadIdx.x] += t;
    __syncthreads();
  }
  bsum[threadIdx.x] = sm[threadIdx.x] - v;
  if (threadIdx.x == NBUCK - 1) bsum[NBUCK] = E;  // sentinel
}

// ---------------- F3: partition edges into bucket regions (packed 4B) ----------------
__global__ __launch_bounds__(512) void k_part(const int* __restrict__ src,
                                              const int* __restrict__ dst,
                                              const int* __restrict__ H,
                                              const int* __restrict__ bstart,
                                              unsigned int* __restrict__ P, int E) {
  __shared__ int cur[NBUCK];
  for (int i = threadIdx.x; i < NBUCK; i += 512)
    cur[i] = bstart[i] + H[(size_t)blockIdx.x * NBUCK + i];
  __syncthreads();
  const int C = (E + NBLK - 1) / NBLK;
  const int lo = blockIdx.x * C, hi = min(E, lo + C);
  for (int e = lo + threadIdx.x; e < hi; e += 512) {
    int d = dst[e], s = src[e];
    int pos = atomicAdd(&cur[d >> 9], 1);
    P[pos] = ((unsigned)(d & 511) << 17) | (unsigned)s;  // needs src < 2^17
  }
}

// ---------------- F4: per-bucket local sort -> srcs + rowptr + deg + dinv ----------------
__global__ __launch_bounds__(512) void k_bucket(const unsigned int* __restrict__ P,
                                                const int* __restrict__ bstart,
                                                int* __restrict__ srcs,
                                                int* __restrict__ rowptr,
                                                int* __restrict__ deg,
                                                float* __restrict__ dinv,
                                                int n) {
  __shared__ int cnt[512], scn[512], cur[512];
  const int b = blockIdx.x;
  const int base = bstart[b], endp = bstart[b + 1];
  cnt[threadIdx.x] = 0;
  __syncthreads();
  for (int e = base + threadIdx.x; e < endp; e += 512)
    atomicAdd(&cnt[P[e] >> 17], 1);
  __syncthreads();
  int v = cnt[threadIdx.x];
  scn[threadIdx.x] = v;
  __syncthreads();
  for (int off = 1; off < 512; off <<= 1) {
    int t = (threadIdx.x >= off) ? scn[threadIdx.x - off] : 0;
    __syncthreads();
    scn[threadIdx.x] += t;
    __syncthreads();
  }
  const int ex = scn[threadIdx.x] - v;   // exclusive within bucket
  cur[threadIdx.x] = ex;
  const int d = (b << 9) + threadIdx.x;
  if (d < n) {
    rowptr[d] = base + ex;
    deg[d] = v;
    dinv[d] = rsqrtf((float)(v + 1));    // +1 self-loop
  }
  __syncthreads();
  for (int e = base + threadIdx.x; e < endp; e += 512) {
    unsigned p = P[e];
    int pos = base + atomicAdd(&cur[p >> 17], 1);
    srcs[pos] = (int)(p & 0x1FFFFu);
  }
}

// ---------------- gather-aggregate: wave per dst node ----------------
__global__ __launch_bounds__(256) void k_gather(const int* __restrict__ srcs,
                                                const int* __restrict__ rowptr,
                                                const int* __restrict__ deg,
                                                const float* __restrict__ dinv,
                                                const float* __restrict__ xw,
                                                const float* __restrict__ bias,
                                                float* __restrict__ out, int n) {
  int lane = threadIdx.x & 63;
  int i = (blockIdx.x * 256 + threadIdx.x) >> 6;
  if (i >= n) return;
  const int c = lane * 2;
  float di = dinv[i];
  const float2 self = *(const float2*)(xw + (size_t)i * 128 + c);
  const float2 bv = *(const float2*)(bias + c);
  float ax = fmaf(di * di, self.x, bv.x);
  float ay = fmaf(di * di, self.y, bv.y);

  int j = rowptr[i];
  int end = j + deg[i];
  for (; j + 4 <= end; j += 4) {
    int s0 = srcs[j], s1 = srcs[j + 1], s2i = srcs[j + 2], s3 = srcs[j + 3];
    float n0 = dinv[s0] * di, n1 = dinv[s1] * di;
    float n2 = dinv[s2i] * di, n3 = dinv[s3] * di;
    const float2 v0 = *(const float2*)(xw + (size_t)s0 * 128 + c);
    const float2 v1 = *(const float2*)(xw + (size_t)s1 * 128 + c);
    const float2 v2 = *(const float2*)(xw + (size_t)s2i * 128 + c);
    const float2 v3 = *(const float2*)(xw + (size_t)s3 * 128 + c);
    ax = fmaf(v0.x, n0, ax); ay = fmaf(v0.y, n0, ay);
    ax = fmaf(v1.x, n1, ax); ay = fmaf(v1.y, n1, ay);
    ax = fmaf(v2.x, n2, ax); ay = fmaf(v2.y, n2, ay);
    ax = fmaf(v3.x, n3, ax); ay = fmaf(v3.y, n3, ay);
  }
  for (; j < end; ++j) {
    int s = srcs[j];
    float nm = dinv[s] * di;
    const float2 v = *(const float2*)(xw + (size_t)s * 128 + c);
    ax = fmaf(v.x, nm, ax); ay = fmaf(v.y, nm, ay);
  }
  float2 o; o.x = ax; o.y = ay;
  *(float2*)(out + (size_t)i * 128 + c) = o;
}

// ---------------- W prep: fragment-major split-bf16 layout ----------------
// wB[((nt*4+kb)*64 + lane)*8 + j] = W[kb*32 + (lane>>4)*8 + j][nt*16 + (lane&15)]
// -> a wave's 64 lanes load CONSECUTIVE 16B chunks (coalesced 1KB/instruction).
__global__ __launch_bounds__(256) void k_wprep(const float* __restrict__ W1,
                                               const float* __restrict__ W2,
                                               const float* __restrict__ W00,
                                               const float* __restrict__ W10,
                                               short* __restrict__ whiT,
                                               short* __restrict__ wloT) {
  const float* Wm = (blockIdx.y == 0) ? W1 : (blockIdx.y == 1) ? W2
                    : (blockIdx.y == 2) ? W00 : W10;
  short* ho = whiT + (size_t)blockIdx.y * 16384;
  short* lo = wloT + (size_t)blockIdx.y * 16384;
  for (int o = threadIdx.x; o < 16384; o += 256) {
    int j  = o & 7;
    int l  = (o >> 3) & 63;
    int kb = (o >> 9) & 3;
    int nt = (o >> 11) & 7;
    int col = nt * 16 + (l & 15);
    int k   = kb * 32 + (l >> 4) * 8 + j;
    float v = Wm[k * 128 + col];
    unsigned short h = f2bf(v);
    ho[o] = (short)h;
    lo[o] = (short)f2bf(v - bf2f(h));
  }
}

// ---------------- MFMA GEMM (split-bf16, 3 products, col-slice waves) ----------------
// Block: 256 thr = 4 waves; 64 rows/block. Wave w owns col-tiles {2w,2w+1} x all 4
// row-tiles: B fragments hoisted to regs (coalesced), reused 4x.
template<bool RELU_A>
__global__ __launch_bounds__(256) void k_gemm_mfma(const float* __restrict__ A,
                                                   const short* __restrict__ wBh,
                                                   const short* __restrict__ wBl,
                                                   float* __restrict__ C, int n) {
  __shared__ short Ahi[64][136];   // 272B row stride: 2-way LDS conflict only (free)
  __shared__ short Alo[64][136];
  const int tid = threadIdx.x;
  const size_t row0 = (size_t)blockIdx.x * 64;

  // stage A -> bf16 hi/lo
  {
    const int c4 = (tid & 31) << 2;
    const int rb = tid >> 5;
#pragma unroll
    for (int p = 0; p < 8; ++p) {
      const int r = rb + p * 8;
      const size_t gr = row0 + r;
      float4 av = make_float4(0.f, 0.f, 0.f, 0.f);
      if (gr < (size_t)n) {
        av = *(const float4*)(A + gr * 128 + c4);
        if (RELU_A) {
          av.x = fmaxf(av.x, 0.f); av.y = fmaxf(av.y, 0.f);
          av.z = fmaxf(av.z, 0.f); av.w = fmaxf(av.w, 0.f);
        }
      }
      short4 h, l;
      h.x = (short)f2bf(av.x); l.x = (short)f2bf(av.x - bf2f((unsigned short)h.x));
      h.y = (short)f2bf(av.y); l.y = (short)f2bf(av.y - bf2f((unsigned short)h.y));
      h.z = (short)f2bf(av.z); l.z = (short)f2bf(av.z - bf2f((unsigned short)h.z));
      h.w = (short)f2bf(av.w); l.w = (short)f2bf(av.w - bf2f((unsigned short)h.w));
      *(short4*)&Ahi[r][c4] = h;
      *(short4*)&Alo[r][c4] = l;
    }
  }
  __syncthreads();

  const int wid = tid >> 6, l = tid & 63;
  const int lo16 = l & 15, kg = l >> 4;

  // hoist B fragments (coalesced: consecutive lanes -> consecutive 16B)
  short8 bh[2][4], bl[2][4];
#pragma unroll
  for (int j = 0; j < 2; ++j)
#pragma unroll
    for (int kb = 0; kb < 4; ++kb) {
      const int off = (((wid * 2 + j) * 4 + kb) * 64 + l) * 8;
      bh[j][kb] = *(const short8*)(wBh + off);
      bl[j][kb] = *(const short8*)(wBl + off);
    }

#pragma unroll
  for (int rt = 0; rt < 4; ++rt) {
    short8 ah[4], al[4];
#pragma unroll
    for (int kb = 0; kb < 4; ++kb) {
      ah[kb] = *(const short8*)&Ahi[rt * 16 + lo16][kb * 32 + kg * 8];
      al[kb] = *(const short8*)&Alo[rt * 16 + lo16][kb * 32 + kg * 8];
    }
    f32x4 acc0 = (f32x4){0.f, 0.f, 0.f, 0.f};
    f32x4 acc1 = (f32x4){0.f, 0.f, 0.f, 0.f};
#pragma unroll
    for (int kb = 0; kb < 4; ++kb) {
      acc0 = __builtin_amdgcn_mfma_f32_16x16x32_bf16(ah[kb], bh[0][kb], acc0, 0, 0, 0);
      acc0 = __builtin_amdgcn_mfma_f32_16x16x32_bf16(ah[kb], bl[0][kb], acc0, 0, 0, 0);
      acc0 = __builtin_amdgcn_mfma_f32_16x16x32_bf16(al[kb], bh[0][kb], acc0, 0, 0, 0);
      acc1 = __builtin_amdgcn_mfma_f32_16x16x32_bf16(ah[kb], bh[1][kb], acc1, 0, 0, 0);
      acc1 = __builtin_amdgcn_mfma_f32_16x16x32_bf16(ah[kb], bl[1][kb], acc1, 0, 0, 0);
      acc1 = __builtin_amdgcn_mfma_f32_16x16x32_bf16(al[kb], bh[1][kb], acc1, 0, 0, 0);
    }
    // C/D: col=lane&15, row=(lane>>4)*4+reg (m89-verified)
    const size_t rbase = row0 + rt * 16 + kg * 4;
    const int col0 = (wid * 2 + 0) * 16 + lo16;
    const int col1 = (wid * 2 + 1) * 16 + lo16;
#pragma unroll
    for (int r = 0; r < 4; ++r) {
      const size_t gr = rbase + r;
      if (gr < (size_t)n) {
        C[gr * 128 + col0] = acc0[r];
        C[gr * 128 + col1] = acc1[r];
      }
    }
  }
}

// ---------------- MFMA fused heads (col-slice waves + LDS cross-wave reduce) ----------------
__global__ __launch_bounds__(256) void k_heads_mfma(const float* __restrict__ rep_pre,
                                                    const short* __restrict__ wB0h,
                                                    const short* __restrict__ wB0l,
                                                    const short* __restrict__ wB1h,
                                                    const short* __restrict__ wB1l,
                                                    const float* __restrict__ b00,
                                                    const float* __restrict__ b10,
                                                    const float* __restrict__ W01,
                                                    const float* __restrict__ b01,
                                                    const float* __restrict__ W11,
                                                    const float* __restrict__ b11,
                                                    const float* __restrict__ Wpp,
                                                    const float* __restrict__ bpp,
                                                    const int* __restrict__ t,
                                                    float* __restrict__ out, int n) {
  __shared__ short Ahi[64][136];
  __shared__ short Alo[64][136];
  __shared__ float red0[4][64];   // per-wave partial row sums, head 0
  __shared__ float red1[4][64];   // head 1
  const int tid = threadIdx.x;
  const size_t row0 = (size_t)blockIdx.x * 64;

  // stage relu(rep) -> bf16 hi/lo
  {
    const int c4 = (tid & 31) << 2;
    const int rb = tid >> 5;
#pragma unroll
    for (int p = 0; p < 8; ++p) {
      const int r = rb + p * 8;
      const size_t gr = row0 + r;
      float4 av = make_float4(0.f, 0.f, 0.f, 0.f);
      if (gr < (size_t)n) {
        av = *(const float4*)(rep_pre + gr * 128 + c4);
        av.x = fmaxf(av.x, 0.f); av.y = fmaxf(av.y, 0.f);
        av.z = fmaxf(av.z, 0.f); av.w = fmaxf(av.w, 0.f);
      }
      short4 h, l;
      h.x = (short)f2bf(av.x); l.x = (short)f2bf(av.x - bf2f((unsigned short)h.x));
      h.y = (short)f2bf(av.y); l.y = (short)f2bf(av.y - bf2f((unsigned short)h.y));
      h.z = (short)f2bf(av.z); l.z = (short)f2bf(av.z - bf2f((unsigned short)h.z));
      h.w = (short)f2bf(av.w); l.w = (short)f2bf(av.w - bf2f((unsigned short)h.w));
      *(short4*)&Ahi[r][c4] = h;
      *(short4*)&Alo[r][c4] = l;
    }
  }
  __syncthreads();

  const int wid = tid >> 6, l = tid & 63;
  const int lo16 = l & 15, kg = l >> 4;
  const int arow = wid * 16 + lo16;

  // ---- p1: rep . Wpp (each lane: its own row, kg-quarter of k; reduce over kg) ----
  {
    float pp = 0.f;
#pragma unroll
    for (int kb = 0; kb < 4; ++kb) {
      const int koff = kb * 32 + kg * 8;
      const short8 ah = *(const short8*)&Ahi[arow][koff];
      const short8 al = *(const short8*)&Alo[arow][koff];
      const float* wp = Wpp + koff;
#pragma unroll
      for (int j = 0; j < 8; ++j) {
        float av = bf2f((unsigned short)ah[j]) + bf2f((unsigned short)al[j]);
        pp = fmaf(av, wp[j], pp);
      }
    }
    pp += __shfl_xor(pp, 16, 64);
    pp += __shfl_xor(pp, 32, 64);
    if (kg == 0) {
      const size_t gr = row0 + arow;
      if (gr < (size_t)n) out[gr] = 1.f / (1.f + expf(-(pp + bpp[0])));
    }
  }

  // ---- heads: wave owns col-tiles {2w,2w+1}, all 4 row-tiles ----
#pragma unroll
  for (int h = 0; h < 2; ++h) {
    const short* wBh = h ? wB1h : wB0h;
    const short* wBl = h ? wB1l : wB0l;
    const float* bb  = h ? b10 : b00;
    const float* w2  = h ? W11 : W01;
    float (*red)[64] = h ? red1 : red0;

    short8 bh[2][4], bl[2][4];
#pragma unroll
    for (int j = 0; j < 2; ++j)
#pragma unroll
      for (int kb = 0; kb < 4; ++kb) {
        const int off = (((wid * 2 + j) * 4 + kb) * 64 + l) * 8;
        bh[j][kb] = *(const short8*)(wBh + off);
        bl[j][kb] = *(const short8*)(wBl + off);
      }
    const int col0 = (wid * 2 + 0) * 16 + lo16;
    const int col1 = (wid * 2 + 1) * 16 + lo16;
    const float bc0 = bb[col0], wc0 = w2[col0];
    const float bc1 = bb[col1], wc1 = w2[col1];

#pragma unroll
    for (int rt = 0; rt < 4; ++rt) {
      short8 ah[4], al[4];
#pragma unroll
      for (int kb = 0; kb < 4; ++kb) {
        ah[kb] = *(const short8*)&Ahi[rt * 16 + lo16][kb * 32 + kg * 8];
        al[kb] = *(const short8*)&Alo[rt * 16 + lo16][kb * 32 + kg * 8];
      }
      f32x4 acc0 = (f32x4){0.f, 0.f, 0.f, 0.f};
      f32x4 acc1 = (f32x4){0.f, 0.f, 0.f, 0.f};
#pragma unroll
      for (int kb = 0; kb < 4; ++kb) {
        acc0 = __builtin_amdgcn_mfma_f32_16x16x32_bf16(ah[kb], bh[0][kb], acc0, 0, 0, 0);
        acc0 = __builtin_amdgcn_mfma_f32_16x16x32_bf16(ah[kb], bl[0][kb], acc0, 0, 0, 0);
        acc0 = __builtin_amdgcn_mfma_f32_16x16x32_bf16(al[kb], bh[0][kb], acc0, 0, 0, 0);
        acc1 = __builtin_amdgcn_mfma_f32_16x16x32_bf16(ah[kb], bh[1][kb], acc1, 0, 0, 0);
        acc1 = __builtin_amdgcn_mfma_f32_16x16x32_bf16(ah[kb], bl[1][kb], acc1, 0, 0, 0);
        acc1 = __builtin_amdgcn_mfma_f32_16x16x32_bf16(al[kb], bh[1][kb], acc1, 0, 0, 0);
      }
#pragma unroll
      for (int r = 0; r < 4; ++r) {
        float v = fmaf(fmaxf(acc0[r] + bc0, 0.f), wc0, 0.f);
        v = fmaf(fmaxf(acc1[r] + bc1, 0.f), wc1, v);
        v += __shfl_xor(v, 1, 64);
        v += __shfl_xor(v, 2, 64);
        v += __shfl_xor(v, 4, 64);
        v += __shfl_xor(v, 8, 64);
        if (lo16 == 0) red[wid][rt * 16 + kg * 4 + r] = v;
      }
    }
  }
  __syncthreads();

  if (tid < 64) {
    const size_t gr = row0 + tid;
    if (gr < (size_t)n) {
      float y0 = red0[0][tid] + red0[1][tid] + red0[2][tid] + red0[3][tid];
      float y1 = red1[0][tid] + red1[1][tid] + red1[2][tid] + red1[3][tid];
      out[n + gr] = (t[gr] > 0) ? (y1 + b11[0]) : (y0 + b01[0]);
    }
  }
}

// ---------------- legacy fp32 path (fallback only) ----------------
__global__ __launch_bounds__(256) void k_deg_init1(int* __restrict__ deg, int n) {
  int i = blockIdx.x * 256 + threadIdx.x;
  if (i < n) deg[i] = 1;
}
__global__ __launch_bounds__(256) void k_deg_count(const int* __restrict__ dst,
                                                   int* __restrict__ deg, int E) {
  int e = blockIdx.x * 256 + threadIdx.x;
  if (e < E) atomicAdd(&deg[dst[e]], 1);
}
__global__ __launch_bounds__(256) void k_dinv0(const int* __restrict__ deg,
                                               float* __restrict__ dinv, int n) {
  int i = blockIdx.x * 256 + threadIdx.x;
  if (i < n) dinv[i] = rsqrtf((float)deg[i]);
}
__global__ __launch_bounds__(256) void k_selfinit(const float* __restrict__ xw,
                                                  const float* __restrict__ dinv,
                                                  const float* __restrict__ bias,
                                                  float* __restrict__ agg, int n) {
  int idx = blockIdx.x * 256 + threadIdx.x;
  if (idx >= n * 32) return;
  int i = idx >> 5;
  int c = (idx & 31) << 2;
  float di = dinv[i];
  float s = di * di;
  const float4 v = *(const float4*)(xw + (size_t)i * 128 + c);
  const float4 b = *(const float4*)(bias + c);
  float4 o;
  o.x = fmaf(s, v.x, b.x);
  o.y = fmaf(s, v.y, b.y);
  o.z = fmaf(s, v.z, b.z);
  o.w = fmaf(s, v.w, b.w);
  *(float4*)(agg + (size_t)i * 128 + c) = o;
}
__global__ __launch_bounds__(256) void k_scatter(const int* __restrict__ src,
                                                 const int* __restrict__ dst,
                                                 const float* __restrict__ dinv,
                                                 const float* __restrict__ xw,
                                                 float* __restrict__ agg, int E) {
  int lane = threadIdx.x & 63;
  int e = (blockIdx.x * 256 + threadIdx.x) >> 6;
  if (e >= E) return;
  int s = src[e], d = dst[e];
  float nrm = dinv[s] * dinv[d];
  const float2 v = *(const float2*)(xw + (size_t)s * 128 + lane * 2);
  float* base = agg + (size_t)d * 128 + lane * 2;
  atomicAdd(base, v.x * nrm);
  atomicAdd(base + 1, v.y * nrm);
}

template<bool RELU_A>
__global__ __launch_bounds__(256) void k_gemm(const float* __restrict__ A,
                                              const float* __restrict__ W,
                                              float* __restrict__ C, int n) {
  __shared__ float As[64][132];
  __shared__ float Ws[128][68];
  const int tid = threadIdx.x;
  const int ct = blockIdx.x;
  const size_t row0 = (size_t)blockIdx.y * 64;
  {
    int c = (tid & 15) << 2;
    int kb = tid >> 4;
#pragma unroll
    for (int p = 0; p < 8; ++p) {
      int k = kb + p * 16;
      const float4 wv = *(const float4*)(W + (size_t)k * 128 + ct * 64 + c);
      *(float4*)&Ws[k][c] = wv;
    }
  }
  {
    int c = (tid & 31) << 2;
    int rb = tid >> 5;
#pragma unroll
    for (int p = 0; p < 8; ++p) {
      int r = rb + p * 8;
      size_t gr = row0 + r;
      float4 av = make_float4(0.f, 0.f, 0.f, 0.f);
      if (gr < (size_t)n) {
        av = *(const float4*)(A + gr * 128 + c);
        if (RELU_A) {
          av.x = fmaxf(av.x, 0.f); av.y = fmaxf(av.y, 0.f);
          av.z = fmaxf(av.z, 0.f); av.w = fmaxf(av.w, 0.f);
        }
      }
      *(float4*)&As[r][c] = av;
    }
  }
  __syncthreads();
  const int tx = tid & 15, ty = tid >> 4;
  const int r0 = ty << 2, c0 = tx << 2;
  float acc[4][4] = {{0.f}};
#pragma unroll 4
  for (int k = 0; k < 128; ++k) {
    const float4 wv = *(const float4*)&Ws[k][c0];
    float a[4];
#pragma unroll
    for (int i = 0; i < 4; ++i) a[i] = As[r0 + i][k];
#pragma unroll
    for (int i = 0; i < 4; ++i) {
      acc[i][0] = fmaf(a[i], wv.x, acc[i][0]);
      acc[i][1] = fmaf(a[i], wv.y, acc[i][1]);
      acc[i][2] = fmaf(a[i], wv.z, acc[i][2]);
      acc[i][3] = fmaf(a[i], wv.w, acc[i][3]);
    }
  }
#pragma unroll
  for (int i = 0; i < 4; ++i) {
    size_t gr = row0 + r0 + i;
    if (gr < (size_t)n) {
      float4 o;
      o.x = acc[i][0]; o.y = acc[i][1]; o.z = acc[i][2]; o.w = acc[i][3];
      *(float4*)(C + gr * 128 + ct * 64 + c0) = o;
    }
  }
}

__global__ __launch_bounds__(256) void k_heads(const float* __restrict__ rep_pre,
                                               const float* __restrict__ W00,
                                               const float* __restrict__ b00,
                                               const float* __restrict__ W10,
                                               const float* __restrict__ b10,
                                               const float* __restrict__ W01,
                                               const float* __restrict__ b01,
                                               const float* __restrict__ W11,
                                               const float* __restrict__ b11,
                                               const float* __restrict__ Wpp,
                                               const float* __restrict__ bpp,
                                               const int* __restrict__ t,
                                               float* __restrict__ out, int n) {
  __shared__ float As[64][132];
  __shared__ float Ws[128][68];
  const int tid = threadIdx.x;
  const size_t row0 = (size_t)blockIdx.x * 64;
  {
    int c = (tid & 31) << 2;
    int rb = tid >> 5;
#pragma unroll
    for (int p = 0; p < 8; ++p) {
      int r = rb + p * 8;
      size_t gr = row0 + r;
      float4 av = make_float4(0.f, 0.f, 0.f, 0.f);
      if (gr < (size_t)n) {
        av = *(const float4*)(rep_pre + gr * 128 + c);
        av.x = fmaxf(av.x, 0.f); av.y = fmaxf(av.y, 0.f);
        av.z = fmaxf(av.z, 0.f); av.w = fmaxf(av.w, 0.f);
      }
      *(float4*)&As[r][c] = av;
    }
  }
  __syncthreads();
  {
    int r = tid >> 2;
    int ko = (tid & 3) * 32;
    float v = 0.f;
#pragma unroll 8
    for (int kk = 0; kk < 32; ++kk) v = fmaf(As[r][ko + kk], Wpp[ko + kk], v);
    v += __shfl_xor(v, 1, 64);
    v += __shfl_xor(v, 2, 64);
    if ((tid & 3) == 0) {
      size_t gr = row0 + r;
      if (gr < (size_t)n) out[gr] = 1.f / (1.f + expf(-(v + bpp[0])));
    }
  }
  const int tx = tid & 15, ty = tid >> 4;
  const int r0 = ty << 2, c0 = tx << 2;
  float yv[2][4];
#pragma unroll
  for (int h = 0; h < 2; ++h) {
    const float* W  = h ? W10 : W00;
    const float* bb = h ? b10 : b00;
    const float* w2 = h ? W11 : W01;
    float part[4] = {0.f, 0.f, 0.f, 0.f};
    for (int half = 0; half < 2; ++half) {
      __syncthreads();
      {
        int c = (tid & 15) << 2;
        int kb = tid >> 4;
#pragma unroll
        for (int p = 0; p < 8; ++p) {
          int k = kb + p * 16;
          const float4 wv = *(const float4*)(W + (size_t)k * 128 + half * 64 + c);
          *(float4*)&Ws[k][c] = wv;
        }
      }
      __syncthreads();
      float acc[4][4] = {{0.f}};
#pragma unroll 4
      for (int k = 0; k < 128; ++k) {
        const float4 wv = *(const float4*)&Ws[k][c0];
        float a[4];
#pragma unroll
        for (int i = 0; i < 4; ++i) a[i] = As[r0 + i][k];
#pragma unroll
        for (int i = 0; i < 4; ++i) {
          acc[i][0] = fmaf(a[i], wv.x, acc[i][0]);
          acc[i][1] = fmaf(a[i], wv.y, acc[i][1]);
          acc[i][2] = fmaf(a[i], wv.z, acc[i][2]);
          acc[i][3] = fmaf(a[i], wv.w, acc[i][3]);
        }
      }
      const float4 bv = *(const float4*)(bb + half * 64 + c0);
      const float4 w2v = *(const float4*)(w2 + half * 64 + c0);
#pragma unroll
      for (int i = 0; i < 4; ++i) {
        part[i] = fmaf(fmaxf(acc[i][0] + bv.x, 0.f), w2v.x, part[i]);
        part[i] = fmaf(fmaxf(acc[i][1] + bv.y, 0.f), w2v.y, part[i]);
        part[i] = fmaf(fmaxf(acc[i][2] + bv.z, 0.f), w2v.z, part[i]);
        part[i] = fmaf(fmaxf(acc[i][3] + bv.w, 0.f), w2v.w, part[i]);
      }
    }
#pragma unroll
    for (int i = 0; i < 4; ++i) {
      float v = part[i];
      v += __shfl_xor(v, 1, 64);
      v += __shfl_xor(v, 2, 64);
      v += __shfl_xor(v, 4, 64);
      v += __shfl_xor(v, 8, 64);
      yv[h][i] = v;
    }
  }
  if (tx == 0) {
#pragma unroll
    for (int i = 0; i < 4; ++i) {
      size_t gr = row0 + r0 + i;
      if (gr < (size_t)n) {
        float v = (t[gr] > 0) ? (yv[1][i] + b11[0]) : (yv[0][i] + b01[0]);
        out[n + gr] = v;
      }
    }
  }
}

extern "C" void kernel_launch(void* const* d_in, const int* in_sizes, int n_in,
                              void* d_out, int out_size, void* d_ws, size_t ws_size,
                              hipStream_t stream) {
  const float* x   = (const float*)d_in[0];
  const int*   t   = (const int*)d_in[1];
  const int*   ei  = (const int*)d_in[3];
  const float* W1  = (const float*)d_in[4];
  const float* b1  = (const float*)d_in[5];
  const float* W2  = (const float*)d_in[6];
  const float* b2  = (const float*)d_in[7];
  const float* W00 = (const float*)d_in[8];
  const float* b00 = (const float*)d_in[9];
  const float* W10 = (const float*)d_in[10];
  const float* b10 = (const float*)d_in[11];
  const float* W01 = (const float*)d_in[12];
  const float* b01 = (const float*)d_in[13];
  const float* W11 = (const float*)d_in[14];
  const float* b11 = (const float*)d_in[15];
  const float* Wpp = (const float*)d_in[16];
  const float* bpp = (const float*)d_in[17];

  const int N = in_sizes[0] / 128;
  const int E = in_sizes[3] / 2;
  const int* srcp = ei;
  const int* dstp = ei + E;

  const size_t S = (size_t)N * 128 * sizeof(float);
  const int nbN = (N + 255) / 256;
  const int nbE = (E + 255) / 256;
  const int nbWaveN = (N + 3) / 4;
  const int nbRow64 = (N + 63) / 64;
  float* out = (float*)d_out;

  // workspace layout
  char* ws = (char*)d_ws;
  float* B1  = (float*)ws; ws += align256(S);
  float* B2  = (float*)ws; ws += align256(S);
  int*   deg = (int*)ws;   ws += align256((size_t)N * 4);
  float* dnv = (float*)ws; ws += align256((size_t)N * 4);
  int*   rowptr = (int*)ws; ws += align256((size_t)N * 4);
  int*   H      = (int*)ws; ws += align256((size_t)NBLK * NBUCK * 4);
  int*   bstart = (int*)ws; ws += align256((size_t)(NBUCK + 1) * 4);
  unsigned int* P = (unsigned int*)ws; ws += align256((size_t)E * 4);
  int*   srcs   = (int*)ws; ws += align256((size_t)E * 4);
  short* whiT   = (short*)ws; ws += align256((size_t)4 * 16384 * 2);
  short* wloT   = (short*)ws; ws += align256((size_t)4 * 16384 * 2);
  size_t need = (size_t)(ws - (char*)d_ws);

  // fast path requires: ws fits, dst < NBUCK*512, src < 2^17
  const bool csr_ok = (need <= ws_size) && (N <= NBUCK * 512) && (N <= (1 << 17));

  if (csr_ok) {
    // ---- W split prep (fragment-major bf16 hi/lo) ----
    k_wprep<<<dim3(1, 4), 256, 0, stream>>>(W1, W2, W00, W10, whiT, wloT);

    // ---- CSR build via two-level bucket sort (no global atomics) ----
    k_hist  <<<NBLK, 512, 0, stream>>>(dstp, H, E);
    k_bscan <<<NBUCK, NBLK, 0, stream>>>(H, bstart);
    k_bstart<<<1, NBUCK, 0, stream>>>(bstart, E);
    k_part  <<<NBLK, 512, 0, stream>>>(srcp, dstp, H, bstart, P, E);
    k_bucket<<<NBUCK, 512, 0, stream>>>(P, bstart, srcs, rowptr, deg, dnv, N);

    // ---- layer 1 ----
    k_gemm_mfma<false><<<nbRow64, 256, 0, stream>>>(x, whiT, wloT, B1, N);
    k_gather<<<nbWaveN, 256, 0, stream>>>(srcs, rowptr, deg, dnv, B1, b1, B2, N);
    // ---- layer 2 ----
    k_gemm_mfma<true><<<nbRow64, 256, 0, stream>>>(B2, whiT + 16384, wloT + 16384, B1, N);
    k_gather<<<nbWaveN, 256, 0, stream>>>(srcs, rowptr, deg, dnv, B1, b2, B2, N);

    // ---- fused heads ----
    k_heads_mfma<<<nbRow64, 256, 0, stream>>>(B2,
        whiT + 2 * 16384, wloT + 2 * 16384, whiT + 3 * 16384, wloT + 3 * 16384,
        b00, b10, W01, b01, W11, b11, Wpp, bpp, t, out, N);
  } else {
    // ---- fallback: atomic scatter + fp32 VALU path ----
    const int nbNode32 = (N * 32 + 255) / 256;
    const int nbWaveE = (int)(((size_t)E * 64 + 255) / 256);
    dim3 gemmGrid(2, nbRow64);
    k_deg_init1<<<nbN, 256, 0, stream>>>(deg, N);
    k_deg_count<<<nbE, 256, 0, stream>>>(dstp, deg, E);
    k_dinv0<<<nbN, 256, 0, stream>>>(deg, dnv, N);
    k_gemm<false><<<gemmGrid, 256, 0, stream>>>(x, W1, B1, N);
    k_selfinit<<<nbNode32, 256, 0, stream>>>(B1, dnv, b1, B2, N);
    k_scatter<<<nbWaveE, 256, 0, stream>>>(srcp, dstp, dnv, B1, B2, E);
    k_gemm<true><<<gemmGrid, 256, 0, stream>>>(B2, W2, B1, N);
    k_selfinit<<<nbNode32, 256, 0, stream>>>(B1, dnv, b2, B2, N);
    k_scatter<<<nbWaveE, 256, 0, stream>>>(srcp, dstp, dnv, B1, B2, E);
    k_heads<<<nbRow64, 256, 0, stream>>>(B2, W00, b00, W10, b10, W01, b01,
                                         W11, b11, Wpp, bpp, t, out, N);
  }
}